// Round 7
// baseline (195.383 us; speedup 1.0000x reference)
//
#include <hip/hip_runtime.h>
#include <hip/hip_bf16.h>

// A=2048 assets, F=2048 flat dim.
//   q = z@Wq^T + bq ; k = z@Wk^T + bk ; v = z@Wv^T + bv
//   S = (q@k^T)/8 ; P = softmax_rows(S) ; h = P@v
// All GEMMs NT (A[m][k].B[n][k]) bf16 MFMA, f32 accum; v materialized as vT.
// K-loop: 3-deep global_load_lds pipeline, COUNTED s_waitcnt vmcnt(8/4/0)
// (never 0 in main loop), raw s_barrier with full sched_barrier(0)+lgkmcnt
// fence discipline (rule #18). All staging full-wave (no exec-masked gloads).
// Linear LDS (no swizzle this round - isolating the pipeline variable).
//
// ws (32 MB) liveness:
//   [0:8)   zb   (dead after V)      -> P (bf16, after scores)
//   [8:16)  Wqb  (dead after QK)     -> vT (bf16, written by V)
//   [16:24) Wkb  (dead after QK)     -> S f32 [16:32)
//   [24:32) Wvb  (dead after V)      -> S cont'd
//   d_out: qb[0:8) + kb[8:16) bf16 (dead after scores) -> final h f32 (PV)

#define AD 2048
#define FD 2048
constexpr float SM_SCALE = 0.125f;   // 64^-0.5

typedef __attribute__((ext_vector_type(8))) short bf16x8;
typedef __attribute__((ext_vector_type(4))) float f32x4;

__device__ __forceinline__ unsigned short f2bf(float f) {
  union { float f; unsigned u; } x; x.f = f;
  unsigned r = x.u + 0x7fffu + ((x.u >> 16) & 1u);   // RNE
  return (unsigned short)(r >> 16);
}

typedef __attribute__((address_space(1))) const void GVOID;
typedef __attribute__((address_space(3))) void LVOID;

__device__ __forceinline__ void gload16(const void* g, void* l) {
  __builtin_amdgcn_global_load_lds((GVOID*)g, (LVOID*)l, 16, 0, 0);
}

struct GemmArgs {
  const void* A;
  const void* B[2];
  const float* bias[2];
  void* out[2];
  float scale;
};

// Fixed geometry: 128x128 tile, BK=32, 4 waves (2x2), wave tile 64x64
// (MREP=NREP=4). Full-wave staging: CA=CB=2 slices/thread, LPS=4 VMEM
// instr/wave/K-step. 3 LDS buffers (48 KB total).
// MODE: 0 = f32 row-major (xscale), 1 = bf16 row-major (+bias), 2 = bf16 C^T (+bias)
template<int MODE>
__global__ __launch_bounds__(256, 3) void gemm_p(GemmArgs args) {
  constexpr int NK = FD / 32;
  __shared__ __hip_bfloat16 lA[3][128 * 32];
  __shared__ __hip_bfloat16 lB[3][128 * 32];

  const int z = blockIdx.z;
  const __hip_bfloat16* __restrict__ A = (const __hip_bfloat16*)args.A;
  const __hip_bfloat16* __restrict__ B = (const __hip_bfloat16*)args.B[z];

  const int t    = threadIdx.x;
  const int bn   = blockIdx.x, bm = blockIdx.y;
  const int lane = t & 63;
  const int wv   = t >> 6;
  const int wr   = wv >> 1;       // 0..1, 64 rows each
  const int wc   = wv & 1;        // 0..1, 64 cols each
  const int fr   = lane & 15;
  const int ko   = (lane >> 4) * 8;

  f32x4 acc[4][4] = {};

  // stage 32-wide K-tile k0 into buffer buf; thread t owns slices t, t+256
  // of each 8KB half (LDS dest = wave-uniform base + lane*16, linear).
  auto STAGE = [&](int k0, int buf) {
    #pragma unroll
    for (int r = 0; r < 2; ++r) {
      const int s = t + r * 256;
      gload16(A + (size_t)(bm * 128 + (s >> 2)) * FD + k0 + (s & 3) * 8, &lA[buf][s * 8]);
    }
    #pragma unroll
    for (int r = 0; r < 2; ++r) {
      const int s = t + r * 256;
      gload16(B + (size_t)(bn * 128 + (s >> 2)) * FD + k0 + (s & 3) * 8, &lB[buf][s * 8]);
    }
  };

  auto COMPUTE = [&](int buf) {
    bf16x8 af[4], bfr[4];
    #pragma unroll
    for (int m = 0; m < 4; ++m)
      af[m] = *reinterpret_cast<const bf16x8*>(&lA[buf][(wr * 64 + m * 16 + fr) * 32 + ko]);
    #pragma unroll
    for (int n = 0; n < 4; ++n)
      bfr[n] = *reinterpret_cast<const bf16x8*>(&lB[buf][(wc * 64 + n * 16 + fr) * 32 + ko]);
    #pragma unroll
    for (int m = 0; m < 4; ++m)
      #pragma unroll
      for (int n = 0; n < 4; ++n)
        acc[m][n] = __builtin_amdgcn_mfma_f32_16x16x32_bf16(af[m], bfr[n], acc[m][n], 0, 0, 0);
  };

  // prologue: 3 tiles in flight (12 loads/wave)
  STAGE(0, 0); STAGE(32, 1); STAGE(64, 2);

  int cur = 0;
  for (int i = 0; i < NK - 3; ++i) {
    // own tile-i loads landed (leave 8 = tiles i+1, i+2 in flight)
    asm volatile("s_waitcnt vmcnt(8)" ::: "memory");
    __builtin_amdgcn_s_barrier();           // all waves' tile-i data in LDS
    __builtin_amdgcn_sched_barrier(0);      // no ds_read hoists above barrier
    COMPUTE(cur);
    asm volatile("s_waitcnt lgkmcnt(0)" ::: "memory");  // all ds_reads retired
    __builtin_amdgcn_sched_barrier(0);
    __builtin_amdgcn_s_barrier();           // every wave done reading buf[cur]
    __builtin_amdgcn_sched_barrier(0);      // no stage hoists above barrier
    STAGE((i + 3) * 32, cur);
    cur = (cur == 2) ? 0 : cur + 1;
  }
  // tail: tiles NK-3, NK-2, NK-1 (no restaging)
  asm volatile("s_waitcnt vmcnt(8)" ::: "memory");
  __builtin_amdgcn_s_barrier();
  __builtin_amdgcn_sched_barrier(0);
  COMPUTE(cur); cur = (cur == 2) ? 0 : cur + 1;
  asm volatile("s_waitcnt vmcnt(4)" ::: "memory");
  __builtin_amdgcn_s_barrier();
  __builtin_amdgcn_sched_barrier(0);
  COMPUTE(cur); cur = (cur == 2) ? 0 : cur + 1;
  asm volatile("s_waitcnt vmcnt(0)" ::: "memory");
  __builtin_amdgcn_s_barrier();
  __builtin_amdgcn_sched_barrier(0);
  COMPUTE(cur);

  // epilogue. C/D mapping (m89-verified): col = lane&15, row = (lane>>4)*4 + j
  const float scale = args.scale;
  const float* __restrict__ bias = args.bias[z];
  const int row0 = bm * 128 + wr * 64 + (lane >> 4) * 4;
  const int col0 = bn * 128 + wc * 64 + fr;

  if constexpr (MODE == 0) {
    float* __restrict__ out = (float*)args.out[z];
    #pragma unroll
    for (int m = 0; m < 4; ++m)
      #pragma unroll
      for (int n = 0; n < 4; ++n) {
        const int cg = col0 + n * 16;
        #pragma unroll
        for (int j = 0; j < 4; ++j)
          out[(size_t)(row0 + m * 16 + j) * FD + cg] = acc[m][n][j] * scale;
      }
  } else if constexpr (MODE == 1) {
    __hip_bfloat16* __restrict__ out = (__hip_bfloat16*)args.out[z];
    #pragma unroll
    for (int m = 0; m < 4; ++m)
      #pragma unroll
      for (int n = 0; n < 4; ++n) {
        const int cg = col0 + n * 16;
        const float badd = bias[cg];
        #pragma unroll
        for (int j = 0; j < 4; ++j) {
          unsigned short b16 = f2bf(acc[m][n][j] + badd);
          out[(size_t)(row0 + m * 16 + j) * FD + cg] = *reinterpret_cast<__hip_bfloat16*>(&b16);
        }
      }
  } else { // MODE == 2: store C^T -> vT[f][a]; 4 consecutive rows = one 8B store
    __hip_bfloat16* __restrict__ out = (__hip_bfloat16*)args.out[z];
    #pragma unroll
    for (int m = 0; m < 4; ++m)
      #pragma unroll
      for (int n = 0; n < 4; ++n) {
        const int cg = col0 + n * 16;   // F index -> row of vT
        const int rg = row0 + m * 16;   // asset index -> col of vT
        const float badd = bias[cg];
        ushort4 pk;
        pk.x = f2bf(acc[m][n][0] + badd);
        pk.y = f2bf(acc[m][n][1] + badd);
        pk.z = f2bf(acc[m][n][2] + badd);
        pk.w = f2bf(acc[m][n][3] + badd);
        *reinterpret_cast<ushort4*>(out + (size_t)cg * AD + rg) = pk;
      }
  }
}

// convert z, Wq, Wk, Wv (f32) -> bf16 [zb | Wqb | Wkb | Wvb], 4M elems each
__global__ __launch_bounds__(256) void cvt_bf16(const float* __restrict__ z,
                                                const float* __restrict__ wq,
                                                const float* __restrict__ wk,
                                                const float* __restrict__ wv,
                                                __hip_bfloat16* __restrict__ dst) {
  const size_t NITEM = (size_t)4 * 4096 * 1024 / 8;
  const size_t step = (size_t)gridDim.x * blockDim.x;
  for (size_t idx = (size_t)blockIdx.x * blockDim.x + threadIdx.x; idx < NITEM; idx += step) {
    const int ten = (int)(idx >> 19);
    const size_t off = (idx & ((1u << 19) - 1)) * 8;
    const float* src = (ten == 0) ? z : (ten == 1) ? wq : (ten == 2) ? wk : wv;
    const float4 a = *reinterpret_cast<const float4*>(src + off);
    const float4 b = *reinterpret_cast<const float4*>(src + off + 4);
    union { unsigned short us[8]; int4 v; } pk;
    pk.us[0] = f2bf(a.x); pk.us[1] = f2bf(a.y); pk.us[2] = f2bf(a.z); pk.us[3] = f2bf(a.w);
    pk.us[4] = f2bf(b.x); pk.us[5] = f2bf(b.y); pk.us[6] = f2bf(b.z); pk.us[7] = f2bf(b.w);
    *reinterpret_cast<int4*>(dst + (size_t)ten * 4096 * 1024 + off) = pk.v;
  }
}

__global__ __launch_bounds__(256) void softmax_rows(const float* __restrict__ S,
                                                    __hip_bfloat16* __restrict__ P) {
  const int row = blockIdx.x;
  const int t = threadIdx.x;
  const float* s = S + (size_t)row * AD + t * 8;
  const float4 v0 = *reinterpret_cast<const float4*>(s);
  const float4 v1 = *reinterpret_cast<const float4*>(s + 4);
  float vals[8] = {v0.x, v0.y, v0.z, v0.w, v1.x, v1.y, v1.z, v1.w};

  float m = vals[0];
  #pragma unroll
  for (int j = 1; j < 8; ++j) m = fmaxf(m, vals[j]);
  #pragma unroll
  for (int off = 32; off >= 1; off >>= 1) m = fmaxf(m, __shfl_xor(m, off));

  __shared__ float redm[4], reds[4];
  if ((t & 63) == 0) redm[t >> 6] = m;
  __syncthreads();
  m = fmaxf(fmaxf(redm[0], redm[1]), fmaxf(redm[2], redm[3]));

  float e[8];
  float sum = 0.f;
  #pragma unroll
  for (int j = 0; j < 8; ++j) { e[j] = __expf(vals[j] - m); sum += e[j]; }
  #pragma unroll
  for (int off = 32; off >= 1; off >>= 1) sum += __shfl_xor(sum, off);
  if ((t & 63) == 0) reds[t >> 6] = sum;
  __syncthreads();
  sum = reds[0] + reds[1] + reds[2] + reds[3];
  const float inv = 1.f / sum;

  union { unsigned short us[8]; int4 v; } pk;
  #pragma unroll
  for (int j = 0; j < 8; ++j) pk.us[j] = f2bf(e[j] * inv);
  *reinterpret_cast<int4*>(P + (size_t)row * AD + t * 8) = pk.v;
}

extern "C" void kernel_launch(void* const* d_in, const int* in_sizes, int n_in,
                              void* d_out, int out_size, void* d_ws, size_t ws_size,
                              hipStream_t stream) {
  const float* z  = (const float*)d_in[0];
  const float* Wq = (const float*)d_in[1];
  const float* bq = (const float*)d_in[2];
  const float* Wk = (const float*)d_in[3];
  const float* bk = (const float*)d_in[4];
  const float* Wv = (const float*)d_in[5];
  const float* bv = (const float*)d_in[6];

  char* ws = (char*)d_ws;
  const size_t MB8 = (size_t)8 * 1024 * 1024;
  __hip_bfloat16* zb  = (__hip_bfloat16*)(ws);            // dead after V
  __hip_bfloat16* Wqb = (__hip_bfloat16*)(ws + MB8);      // dead after QK
  __hip_bfloat16* Wkb = (__hip_bfloat16*)(ws + 2*MB8);    // dead after QK
  __hip_bfloat16* Wvb = (__hip_bfloat16*)(ws + 3*MB8);    // dead after V
  __hip_bfloat16* vT  = (__hip_bfloat16*)(ws + MB8);      // over Wqb
  float*          S   = (float*)(ws + 2*MB8);             // over Wkb+Wvb (16MB)
  __hip_bfloat16* P   = (__hip_bfloat16*)(ws);            // over zb
  __hip_bfloat16* qb  = (__hip_bfloat16*)d_out;           // d_out scratch [0:8)MB
  __hip_bfloat16* kb  = (__hip_bfloat16*)d_out + (size_t)AD * FD;  // [8:16)MB

  // 0) convert all four tensors to bf16
  cvt_bf16<<<dim3(2048), dim3(256), 0, stream>>>(z, Wq, Wk, Wv, (__hip_bfloat16*)ws);

  // 1) fused QK: 512 blocks (~2/CU)
  {
    GemmArgs a;
    a.A = zb;
    a.B[0] = Wqb;  a.B[1] = Wkb;
    a.bias[0] = bq; a.bias[1] = bk;
    a.out[0] = qb;  a.out[1] = kb;
    a.scale = 1.0f;
    gemm_p<1><<<dim3(AD/128, AD/128, 2), dim3(256), 0, stream>>>(a);
  }
  // 2) V -> vT (over Wqb): 256 blocks
  {
    GemmArgs a = {};
    a.A = zb;
    a.B[0] = Wvb;
    a.bias[0] = bv;
    a.out[0] = vT;
    a.scale = 1.0f;
    gemm_p<2><<<dim3(AD/128, AD/128, 1), dim3(256), 0, stream>>>(a);
  }
  // 3) scores = (qb @ kb^T)/8 -> f32 S (over Wkb+Wvb): 256 blocks
  {
    GemmArgs a = {};
    a.A = qb;
    a.B[0] = kb;
    a.bias[0] = nullptr;
    a.out[0] = S;
    a.scale = SM_SCALE;
    gemm_p<0><<<dim3(AD/128, AD/128, 1), dim3(256), 0, stream>>>(a);
  }
  // 4) row softmax -> P bf16 (over zb)
  softmax_rows<<<dim3(AD), dim3(256), 0, stream>>>(S, P);
  // 5) h = P @ vT^T -> f32 d_out (over qb/kb)
  {
    GemmArgs a = {};
    a.A = P;
    a.B[0] = vT;
    a.bias[0] = nullptr;
    a.out[0] = d_out;
    a.scale = 1.0f;
    gemm_p<0><<<dim3(AD/128, AD/128, 1), dim3(256), 0, stream>>>(a);
  }
}

// Round 8
// 168.970 us; speedup vs baseline: 1.1563x; 1.1563x over previous
//
#include <hip/hip_runtime.h>
#include <hip/hip_bf16.h>

// A=2048 assets, F=2048 flat dim.
//   q = z@Wq^T + bq ; k = z@Wk^T + bk ; v = z@Wv^T + bv
//   S = (q@k^T)/8 ; P = softmax_rows(S) ; h = P@v
// All GEMMs NT (A[m][k].B[n][k]) bf16 MFMA, f32 accum; v materialized as vT.
// Structure: round-5-proven simple 2-phase dbuf (STAGE next -> COMPUTE cur ->
// one __syncthreads). No asm fences (round-7 lesson: pinning regresses).
// QKV fused z=3 with (4,4) 4-wave 128^2 tiles (balanced LDS:MFMA ratio),
// scores/PV with measured-best 128x64 8-wave tiles at 512 blocks.
//
// ws (32 MB) liveness:
//   [0:8)   zb   (dead after QKV)  -> S f32 [0:16)
//   [8:16)  Wqb  (dead after QKV)  ->   S cont'd
//   [16:24) Wkb  (dead after QKV)  -> P bf16
//   [24:32) vT   (written by QKV z=2, live until PV)
//   d_out: qb[0:8) + kb[8:16) bf16 (dead after scores) -> final h f32 (PV)
// Wv is consumed f32 directly (reg-stage+cvt B-side, z=2 blocks only).

#define AD 2048
#define FD 2048
constexpr float SM_SCALE = 0.125f;   // 64^-0.5

typedef __attribute__((ext_vector_type(8))) short bf16x8;
typedef __attribute__((ext_vector_type(4))) float f32x4;

__device__ __forceinline__ unsigned short f2bf(float f) {
  union { float f; unsigned u; } x; x.f = f;
  unsigned r = x.u + 0x7fffu + ((x.u >> 16) & 1u);   // RNE
  return (unsigned short)(r >> 16);
}

typedef __attribute__((address_space(1))) const void GVOID;
typedef __attribute__((address_space(3))) void LVOID;

__device__ __forceinline__ void gload16(const void* g, void* l) {
  __builtin_amdgcn_global_load_lds((GVOID*)g, (LVOID*)l, 16, 0, 0);
}

struct GemmArgs {
  const void* A;
  const void* B[3];
  const float* bias[3];
  void* out[3];
  int outmode[3];   // 0 = f32 row-major (xscale), 1 = bf16 row-major (+bias), 2 = bf16 C^T (+bias)
  int bf32mask;     // bit z: B[z] is f32 (reg-stage + cvt)
  float scale;
};

// Wave grid WROWS x WCOLS, wave tile (MREP*16) x (NREP*16), BK=32, dbuf LDS.
// FORCE_MODE >= 0: compile single epilogue; -1: runtime args.outmode[z].
// W2: min waves per EU for __launch_bounds__.
template<int WROWS, int WCOLS, int MREP, int NREP, int FORCE_MODE, bool MIXEDB, int W2>
__global__ __launch_bounds__(WROWS*WCOLS*64, W2) void gemm_d(GemmArgs args) {
  constexpr int NT = WROWS * WCOLS * 64;
  constexpr int BM = WROWS * MREP * 16;
  constexpr int BN = WCOLS * NREP * 16;
  constexpr int SA = BM * 4;            // 16B slices per A K-tile
  constexpr int SB = BN * 4;
  static_assert(SA >= NT && SA % NT == 0, "A staging full-coverage");
  static_assert(SB >= NT || (SB % 64 == 0), "B staging wave-granular");

  __shared__ __hip_bfloat16 lA[2][BM * 32];
  __shared__ __hip_bfloat16 lB[2][BN * 32];

  const int z = blockIdx.z;
  const __hip_bfloat16* __restrict__ A = (const __hip_bfloat16*)args.A;
  const __hip_bfloat16* __restrict__ B = (const __hip_bfloat16*)args.B[z];
  const float*          __restrict__ Bf = (const float*)args.B[z];

  const int t    = threadIdx.x;
  const int bn   = blockIdx.x, bm = blockIdx.y;
  const int lane = t & 63;
  const int wv   = t >> 6;
  const int wr   = wv / WCOLS;
  const int wc   = wv % WCOLS;
  const int fr   = lane & 15;
  const int ko   = (lane >> 4) * 8;

  bool dof32 = false;
  if constexpr (MIXEDB) dof32 = (args.bf32mask >> z) & 1;

  f32x4 acc[MREP][NREP] = {};

  auto STAGE = [&](int k0, int buf) {
    #pragma unroll
    for (int r = 0; r < SA / NT; ++r) {
      const int s = t + r * NT;
      gload16(A + (size_t)(bm * BM + (s >> 2)) * FD + k0 + (s & 3) * 8, &lA[buf][s * 8]);
    }
    if constexpr (MIXEDB) {
      if (dof32) {
        #pragma unroll
        for (int r = 0; r < (SB + NT - 1) / NT; ++r) {
          const int s = t + r * NT;
          if (SB >= NT || t < SB) {
            const float* src = Bf + (size_t)(bn * BN + (s >> 2)) * FD + k0 + (s & 3) * 8;
            const float4 x = *reinterpret_cast<const float4*>(src);
            const float4 y = *reinterpret_cast<const float4*>(src + 4);
            union { unsigned short us[8]; int4 v; } pk;
            pk.us[0] = f2bf(x.x); pk.us[1] = f2bf(x.y); pk.us[2] = f2bf(x.z); pk.us[3] = f2bf(x.w);
            pk.us[4] = f2bf(y.x); pk.us[5] = f2bf(y.y); pk.us[6] = f2bf(y.z); pk.us[7] = f2bf(y.w);
            *reinterpret_cast<int4*>(&lB[buf][s * 8]) = pk.v;
          }
        }
        return;
      }
    }
    #pragma unroll
    for (int r = 0; r < (SB + NT - 1) / NT; ++r) {
      const int s = t + r * NT;
      if (SB >= NT || t < SB)   // wave-granular mask (SB % 64 == 0)
        gload16(B + (size_t)(bn * BN + (s >> 2)) * FD + k0 + (s & 3) * 8, &lB[buf][s * 8]);
    }
  };

  auto COMPUTE = [&](int buf) {
    bf16x8 af[MREP], bfr[NREP];
    #pragma unroll
    for (int m = 0; m < MREP; ++m)
      af[m] = *reinterpret_cast<const bf16x8*>(&lA[buf][(wr * (MREP * 16) + m * 16 + fr) * 32 + ko]);
    #pragma unroll
    for (int n = 0; n < NREP; ++n)
      bfr[n] = *reinterpret_cast<const bf16x8*>(&lB[buf][(wc * (NREP * 16) + n * 16 + fr) * 32 + ko]);
    #pragma unroll
    for (int m = 0; m < MREP; ++m)
      #pragma unroll
      for (int n = 0; n < NREP; ++n)
        acc[m][n] = __builtin_amdgcn_mfma_f32_16x16x32_bf16(af[m], bfr[n], acc[m][n], 0, 0, 0);
  };

  STAGE(0, 0);
  __syncthreads();
  int cur = 0;
  for (int k0 = 32; k0 < FD; k0 += 32) {
    STAGE(k0, cur ^ 1);     // prefetch next tile (in flight during COMPUTE)
    COMPUTE(cur);
    __syncthreads();        // drains prefetch + all frag reads of cur
    cur ^= 1;
  }
  COMPUTE(cur);

  // Epilogue. C/D mapping (m89-verified): col = lane&15, row = (lane>>4)*4 + j
  const float scale = args.scale;
  const float* __restrict__ bias = args.bias[z];
  const int mode = (FORCE_MODE >= 0) ? FORCE_MODE : args.outmode[z];
  const int row0 = bm * BM + wr * (MREP * 16) + (lane >> 4) * 4;
  const int col0 = bn * BN + wc * (NREP * 16) + fr;

  if (mode == 0) {
    float* __restrict__ out = (float*)args.out[z];
    #pragma unroll
    for (int m = 0; m < MREP; ++m)
      #pragma unroll
      for (int n = 0; n < NREP; ++n) {
        const int cg = col0 + n * 16;
        #pragma unroll
        for (int j = 0; j < 4; ++j)
          out[(size_t)(row0 + m * 16 + j) * FD + cg] = acc[m][n][j] * scale;
      }
  } else if (mode == 1) {
    __hip_bfloat16* __restrict__ out = (__hip_bfloat16*)args.out[z];
    #pragma unroll
    for (int m = 0; m < MREP; ++m)
      #pragma unroll
      for (int n = 0; n < NREP; ++n) {
        const int cg = col0 + n * 16;
        const float badd = bias[cg];
        #pragma unroll
        for (int j = 0; j < 4; ++j) {
          unsigned short b16 = f2bf(acc[m][n][j] + badd);
          out[(size_t)(row0 + m * 16 + j) * FD + cg] = *reinterpret_cast<__hip_bfloat16*>(&b16);
        }
      }
  } else { // mode == 2: store C^T -> vT[f][a]; 4 consecutive rows = one 8B store
    __hip_bfloat16* __restrict__ out = (__hip_bfloat16*)args.out[z];
    #pragma unroll
    for (int m = 0; m < MREP; ++m)
      #pragma unroll
      for (int n = 0; n < NREP; ++n) {
        const int cg = col0 + n * 16;   // F index -> row of vT
        const int rg = row0 + m * 16;   // asset index -> col of vT
        const float badd = bias[cg];
        ushort4 pk;
        pk.x = f2bf(acc[m][n][0] + badd);
        pk.y = f2bf(acc[m][n][1] + badd);
        pk.z = f2bf(acc[m][n][2] + badd);
        pk.w = f2bf(acc[m][n][3] + badd);
        *reinterpret_cast<ushort4*>(out + (size_t)cg * AD + rg) = pk;
      }
  }
}

// convert z, Wq, Wk (f32) -> bf16 [zb | Wqb | Wkb], 4M elems each
__global__ __launch_bounds__(256) void cvt_bf16(const float* __restrict__ z,
                                                const float* __restrict__ wq,
                                                const float* __restrict__ wk,
                                                __hip_bfloat16* __restrict__ dst) {
  const size_t NITEM = (size_t)3 * 4096 * 1024 / 8;
  const size_t step = (size_t)gridDim.x * blockDim.x;
  for (size_t idx = (size_t)blockIdx.x * blockDim.x + threadIdx.x; idx < NITEM; idx += step) {
    const int ten = (int)(idx >> 19);
    const size_t off = (idx & ((1u << 19) - 1)) * 8;
    const float* src = (ten == 0) ? z : (ten == 1) ? wq : wk;
    const float4 a = *reinterpret_cast<const float4*>(src + off);
    const float4 b = *reinterpret_cast<const float4*>(src + off + 4);
    union { unsigned short us[8]; int4 v; } pk;
    pk.us[0] = f2bf(a.x); pk.us[1] = f2bf(a.y); pk.us[2] = f2bf(a.z); pk.us[3] = f2bf(a.w);
    pk.us[4] = f2bf(b.x); pk.us[5] = f2bf(b.y); pk.us[6] = f2bf(b.z); pk.us[7] = f2bf(b.w);
    *reinterpret_cast<int4*>(dst + (size_t)ten * 4096 * 1024 + off) = pk.v;
  }
}

__global__ __launch_bounds__(256) void softmax_rows(const float* __restrict__ S,
                                                    __hip_bfloat16* __restrict__ P) {
  const int row = blockIdx.x;
  const int t = threadIdx.x;
  const float* s = S + (size_t)row * AD + t * 8;
  const float4 v0 = *reinterpret_cast<const float4*>(s);
  const float4 v1 = *reinterpret_cast<const float4*>(s + 4);
  float vals[8] = {v0.x, v0.y, v0.z, v0.w, v1.x, v1.y, v1.z, v1.w};

  float m = vals[0];
  #pragma unroll
  for (int j = 1; j < 8; ++j) m = fmaxf(m, vals[j]);
  #pragma unroll
  for (int off = 32; off >= 1; off >>= 1) m = fmaxf(m, __shfl_xor(m, off));

  __shared__ float redm[4], reds[4];
  if ((t & 63) == 0) redm[t >> 6] = m;
  __syncthreads();
  m = fmaxf(fmaxf(redm[0], redm[1]), fmaxf(redm[2], redm[3]));

  float e[8];
  float sum = 0.f;
  #pragma unroll
  for (int j = 0; j < 8; ++j) { e[j] = __expf(vals[j] - m); sum += e[j]; }
  #pragma unroll
  for (int off = 32; off >= 1; off >>= 1) sum += __shfl_xor(sum, off);
  if ((t & 63) == 0) reds[t >> 6] = sum;
  __syncthreads();
  sum = reds[0] + reds[1] + reds[2] + reds[3];
  const float inv = 1.f / sum;

  union { unsigned short us[8]; int4 v; } pk;
  #pragma unroll
  for (int j = 0; j < 8; ++j) pk.us[j] = f2bf(e[j] * inv);
  *reinterpret_cast<int4*>(P + (size_t)row * AD + t * 8) = pk.v;
}

extern "C" void kernel_launch(void* const* d_in, const int* in_sizes, int n_in,
                              void* d_out, int out_size, void* d_ws, size_t ws_size,
                              hipStream_t stream) {
  const float* z  = (const float*)d_in[0];
  const float* Wq = (const float*)d_in[1];
  const float* bq = (const float*)d_in[2];
  const float* Wk = (const float*)d_in[3];
  const float* bk = (const float*)d_in[4];
  const float* Wv = (const float*)d_in[5];
  const float* bv = (const float*)d_in[6];

  char* ws = (char*)d_ws;
  const size_t MB8 = (size_t)8 * 1024 * 1024;
  __hip_bfloat16* zb  = (__hip_bfloat16*)(ws);            // dead after QKV
  __hip_bfloat16* Wqb = (__hip_bfloat16*)(ws + MB8);      // dead after QKV
  __hip_bfloat16* Wkb = (__hip_bfloat16*)(ws + 2*MB8);    // dead after QKV
  __hip_bfloat16* vT  = (__hip_bfloat16*)(ws + 3*MB8);    // live until PV
  float*          S   = (float*)(ws);                     // over zb+Wqb (16MB)
  __hip_bfloat16* P   = (__hip_bfloat16*)(ws + 2*MB8);    // over Wkb
  __hip_bfloat16* qb  = (__hip_bfloat16*)d_out;           // d_out scratch [0:8)MB
  __hip_bfloat16* kb  = (__hip_bfloat16*)d_out + (size_t)AD * FD;  // [8:16)MB

  // 0) convert z, Wq, Wk to bf16 (Wv consumed f32 in-kernel)
  cvt_bf16<<<dim3(2048), dim3(256), 0, stream>>>(z, Wq, Wk, (__hip_bfloat16*)ws);

  // 1) fused QKV: (4,4) 4-wave 128^2, 768 blocks (~3/CU, 12 waves/CU)
  {
    GemmArgs a;
    a.A = zb;
    a.B[0] = Wqb; a.B[1] = Wkb; a.B[2] = Wv;
    a.bias[0] = bq; a.bias[1] = bk; a.bias[2] = bv;
    a.out[0] = qb; a.out[1] = kb; a.out[2] = vT;
    a.outmode[0] = 1; a.outmode[1] = 1; a.outmode[2] = 2;
    a.bf32mask = 0b100;
    a.scale = 1.0f;
    gemm_d<2, 2, 4, 4, -1, true, 3><<<dim3(AD/128, AD/128, 3), dim3(256), 0, stream>>>(a);
  }
  // 2) scores = (qb @ kb^T)/8 -> f32 S ; 128x64 8-wave, 512 blocks (~2/CU)
  {
    GemmArgs a = {};
    a.A = qb;
    a.B[0] = kb;
    a.bias[0] = nullptr;
    a.out[0] = S;
    a.outmode[0] = 0;
    a.bf32mask = 0;
    a.scale = SM_SCALE;
    gemm_d<4, 2, 2, 2, 0, false, 4><<<dim3(AD/64, AD/128, 1), dim3(512), 0, stream>>>(a);
  }
  // 3) row softmax -> P bf16 (over Wkb)
  softmax_rows<<<dim3(AD), dim3(256), 0, stream>>>(S, P);
  // 4) h = P @ vT^T -> f32 d_out ; 128x64 8-wave, 512 blocks (~2/CU)
  {
    GemmArgs a = {};
    a.A = P;
    a.B[0] = vT;
    a.bias[0] = nullptr;
    a.out[0] = d_out;
    a.outmode[0] = 0;
    a.bf32mask = 0;
    a.scale = 1.0f;
    gemm_d<4, 2, 2, 2, 0, false, 4><<<dim3(AD/64, AD/128, 1), dim3(512), 0, stream>>>(a);
  }
}

// Round 9
// 164.968 us; speedup vs baseline: 1.1844x; 1.0243x over previous
//
#include <hip/hip_runtime.h>
#include <hip/hip_bf16.h>

// A=2048 assets, F=2048 flat dim.
//   q = z@Wq^T + bq ; k = z@Wk^T + bk ; v = z@Wv^T + bv
//   S = (q@k^T)/8 ; P = softmax_rows(S) ; h = P@v
// All GEMMs NT (A[m][k].B[n][k]) bf16 MFMA, f32 accum; v materialized as vT.
// Round 9 = round 8 + ONE change: conflict-free LDS XOR swizzle
//   physical_slot = logical_slot ^ ((row>>1)&3)   (slot = 16B k-group)
// realized as pre-swizzled GLOBAL source column (gload_lds dest stays linear,
// rule #21 / m173) + the same XOR on frag-read addresses. Bank math:
// bank_group = 16*(row&1) + 4*slot -> 16 consecutive rows cover all 8 groups
// twice -> 2-way (free, m136) instead of 8-way.
//
// ws (32 MB) liveness:
//   [0:8)   zb   (dead after QKV)  -> S f32 [0:16)
//   [8:16)  Wqb  (dead after QKV)  ->   S cont'd
//   [16:24) Wkb  (dead after QKV)  -> P bf16
//   [24:32) vT   (written by QKV z=2, live until PV)
//   d_out: qb[0:8) + kb[8:16) bf16 (dead after scores) -> final h f32 (PV)
// Wv is consumed f32 directly (reg-stage+cvt B-side, z=2 blocks only).

#define AD 2048
#define FD 2048
constexpr float SM_SCALE = 0.125f;   // 64^-0.5

typedef __attribute__((ext_vector_type(8))) short bf16x8;
typedef __attribute__((ext_vector_type(4))) float f32x4;

__device__ __forceinline__ unsigned short f2bf(float f) {
  union { float f; unsigned u; } x; x.f = f;
  unsigned r = x.u + 0x7fffu + ((x.u >> 16) & 1u);   // RNE
  return (unsigned short)(r >> 16);
}

typedef __attribute__((address_space(1))) const void GVOID;
typedef __attribute__((address_space(3))) void LVOID;

__device__ __forceinline__ void gload16(const void* g, void* l) {
  __builtin_amdgcn_global_load_lds((GVOID*)g, (LVOID*)l, 16, 0, 0);
}

struct GemmArgs {
  const void* A;
  const void* B[3];
  const float* bias[3];
  void* out[3];
  int outmode[3];   // 0 = f32 row-major (xscale), 1 = bf16 row-major (+bias), 2 = bf16 C^T (+bias)
  int bf32mask;     // bit z: B[z] is f32 (reg-stage + cvt)
  float scale;
};

// Wave grid WROWS x WCOLS, wave tile (MREP*16) x (NREP*16), BK=32, dbuf LDS.
// FORCE_MODE >= 0: compile single epilogue; -1: runtime args.outmode[z].
template<int WROWS, int WCOLS, int MREP, int NREP, int FORCE_MODE, bool MIXEDB, int W2>
__global__ __launch_bounds__(WROWS*WCOLS*64, W2) void gemm_d(GemmArgs args) {
  constexpr int NT = WROWS * WCOLS * 64;
  constexpr int BM = WROWS * MREP * 16;
  constexpr int BN = WCOLS * NREP * 16;
  constexpr int SA = BM * 4;            // 16B slices per A K-tile
  constexpr int SB = BN * 4;
  static_assert(SA >= NT && SA % NT == 0, "A staging full-coverage");
  static_assert(SB >= NT || (SB % 64 == 0), "B staging wave-granular");

  __shared__ __hip_bfloat16 lA[2][BM * 32];
  __shared__ __hip_bfloat16 lB[2][BN * 32];

  const int z = blockIdx.z;
  const __hip_bfloat16* __restrict__ A = (const __hip_bfloat16*)args.A;
  const __hip_bfloat16* __restrict__ B = (const __hip_bfloat16*)args.B[z];
  const float*          __restrict__ Bf = (const float*)args.B[z];

  const int t    = threadIdx.x;
  const int bn   = blockIdx.x, bm = blockIdx.y;
  const int lane = t & 63;
  const int wv   = t >> 6;
  const int wr   = wv / WCOLS;
  const int wc   = wv % WCOLS;
  const int fr   = lane & 15;
  const int s2   = lane >> 4;          // logical 16B k-group 0..3

  bool dof32 = false;
  if constexpr (MIXEDB) dof32 = (args.bf32mask >> z) & 1;

  f32x4 acc[MREP][NREP] = {};

  // swizzled source column for slice s (row = s>>2, physical slot = s&3):
  // physical slot p holds logical group p ^ ((row>>1)&3)
  auto scol = [](int s) { return (((s & 3) ^ ((s >> 3) & 3)) * 8); };

  auto STAGE = [&](int k0, int buf) {
    #pragma unroll
    for (int r = 0; r < SA / NT; ++r) {
      const int s = t + r * NT;
      gload16(A + (size_t)(bm * BM + (s >> 2)) * FD + k0 + scol(s), &lA[buf][s * 8]);
    }
    if constexpr (MIXEDB) {
      if (dof32) {
        #pragma unroll
        for (int r = 0; r < (SB + NT - 1) / NT; ++r) {
          const int s = t + r * NT;
          if (SB >= NT || t < SB) {
            const float* src = Bf + (size_t)(bn * BN + (s >> 2)) * FD + k0 + scol(s);
            const float4 x = *reinterpret_cast<const float4*>(src);
            const float4 y = *reinterpret_cast<const float4*>(src + 4);
            union { unsigned short us[8]; int4 v; } pk;
            pk.us[0] = f2bf(x.x); pk.us[1] = f2bf(x.y); pk.us[2] = f2bf(x.z); pk.us[3] = f2bf(x.w);
            pk.us[4] = f2bf(y.x); pk.us[5] = f2bf(y.y); pk.us[6] = f2bf(y.z); pk.us[7] = f2bf(y.w);
            *reinterpret_cast<int4*>(&lB[buf][s * 8]) = pk.v;
          }
        }
        return;
      }
    }
    #pragma unroll
    for (int r = 0; r < (SB + NT - 1) / NT; ++r) {
      const int s = t + r * NT;
      if (SB >= NT || t < SB)   // wave-granular mask (SB % 64 == 0)
        gload16(B + (size_t)(bn * BN + (s >> 2)) * FD + k0 + scol(s), &lB[buf][s * 8]);
    }
  };

  auto COMPUTE = [&](int buf) {
    bf16x8 af[MREP], bfr[NREP];
    #pragma unroll
    for (int m = 0; m < MREP; ++m) {
      const int row = wr * (MREP * 16) + m * 16 + fr;
      af[m] = *reinterpret_cast<const bf16x8*>(
          &lA[buf][row * 32 + ((s2 ^ ((row >> 1) & 3)) * 8)]);
    }
    #pragma unroll
    for (int n = 0; n < NREP; ++n) {
      const int row = wc * (NREP * 16) + n * 16 + fr;
      bfr[n] = *reinterpret_cast<const bf16x8*>(
          &lB[buf][row * 32 + ((s2 ^ ((row >> 1) & 3)) * 8)]);
    }
    #pragma unroll
    for (int m = 0; m < MREP; ++m)
      #pragma unroll
      for (int n = 0; n < NREP; ++n)
        acc[m][n] = __builtin_amdgcn_mfma_f32_16x16x32_bf16(af[m], bfr[n], acc[m][n], 0, 0, 0);
  };

  STAGE(0, 0);
  __syncthreads();
  int cur = 0;
  for (int k0 = 32; k0 < FD; k0 += 32) {
    STAGE(k0, cur ^ 1);     // prefetch next tile (in flight during COMPUTE)
    COMPUTE(cur);
    __syncthreads();        // drains prefetch + all frag reads of cur
    cur ^= 1;
  }
  COMPUTE(cur);

  // Epilogue. C/D mapping (m89-verified): col = lane&15, row = (lane>>4)*4 + j
  const float scale = args.scale;
  const float* __restrict__ bias = args.bias[z];
  const int mode = (FORCE_MODE >= 0) ? FORCE_MODE : args.outmode[z];
  const int row0 = bm * BM + wr * (MREP * 16) + (lane >> 4) * 4;
  const int col0 = bn * BN + wc * (NREP * 16) + fr;

  if (mode == 0) {
    float* __restrict__ out = (float*)args.out[z];
    #pragma unroll
    for (int m = 0; m < MREP; ++m)
      #pragma unroll
      for (int n = 0; n < NREP; ++n) {
        const int cg = col0 + n * 16;
        #pragma unroll
        for (int j = 0; j < 4; ++j)
          out[(size_t)(row0 + m * 16 + j) * FD + cg] = acc[m][n][j] * scale;
      }
  } else if (mode == 1) {
    __hip_bfloat16* __restrict__ out = (__hip_bfloat16*)args.out[z];
    #pragma unroll
    for (int m = 0; m < MREP; ++m)
      #pragma unroll
      for (int n = 0; n < NREP; ++n) {
        const int cg = col0 + n * 16;
        const float badd = bias[cg];
        #pragma unroll
        for (int j = 0; j < 4; ++j) {
          unsigned short b16 = f2bf(acc[m][n][j] + badd);
          out[(size_t)(row0 + m * 16 + j) * FD + cg] = *reinterpret_cast<__hip_bfloat16*>(&b16);
        }
      }
  } else { // mode == 2: store C^T -> vT[f][a]; 4 consecutive rows = one 8B store
    __hip_bfloat16* __restrict__ out = (__hip_bfloat16*)args.out[z];
    #pragma unroll
    for (int m = 0; m < MREP; ++m)
      #pragma unroll
      for (int n = 0; n < NREP; ++n) {
        const int cg = col0 + n * 16;   // F index -> row of vT
        const int rg = row0 + m * 16;   // asset index -> col of vT
        const float badd = bias[cg];
        ushort4 pk;
        pk.x = f2bf(acc[m][n][0] + badd);
        pk.y = f2bf(acc[m][n][1] + badd);
        pk.z = f2bf(acc[m][n][2] + badd);
        pk.w = f2bf(acc[m][n][3] + badd);
        *reinterpret_cast<ushort4*>(out + (size_t)cg * AD + rg) = pk;
      }
  }
}

// convert z, Wq, Wk (f32) -> bf16 [zb | Wqb | Wkb], 4M elems each
__global__ __launch_bounds__(256) void cvt_bf16(const float* __restrict__ z,
                                                const float* __restrict__ wq,
                                                const float* __restrict__ wk,
                                                __hip_bfloat16* __restrict__ dst) {
  const size_t NITEM = (size_t)3 * 4096 * 1024 / 8;
  const size_t step = (size_t)gridDim.x * blockDim.x;
  for (size_t idx = (size_t)blockIdx.x * blockDim.x + threadIdx.x; idx < NITEM; idx += step) {
    const int ten = (int)(idx >> 19);
    const size_t off = (idx & ((1u << 19) - 1)) * 8;
    const float* src = (ten == 0) ? z : (ten == 1) ? wq : wk;
    const float4 a = *reinterpret_cast<const float4*>(src + off);
    const float4 b = *reinterpret_cast<const float4*>(src + off + 4);
    union { unsigned short us[8]; int4 v; } pk;
    pk.us[0] = f2bf(a.x); pk.us[1] = f2bf(a.y); pk.us[2] = f2bf(a.z); pk.us[3] = f2bf(a.w);
    pk.us[4] = f2bf(b.x); pk.us[5] = f2bf(b.y); pk.us[6] = f2bf(b.z); pk.us[7] = f2bf(b.w);
    *reinterpret_cast<int4*>(dst + (size_t)ten * 4096 * 1024 + off) = pk.v;
  }
}

__global__ __launch_bounds__(256) void softmax_rows(const float* __restrict__ S,
                                                    __hip_bfloat16* __restrict__ P) {
  const int row = blockIdx.x;
  const int t = threadIdx.x;
  const float* s = S + (size_t)row * AD + t * 8;
  const float4 v0 = *reinterpret_cast<const float4*>(s);
  const float4 v1 = *reinterpret_cast<const float4*>(s + 4);
  float vals[8] = {v0.x, v0.y, v0.z, v0.w, v1.x, v1.y, v1.z, v1.w};

  float m = vals[0];
  #pragma unroll
  for (int j = 1; j < 8; ++j) m = fmaxf(m, vals[j]);
  #pragma unroll
  for (int off = 32; off >= 1; off >>= 1) m = fmaxf(m, __shfl_xor(m, off));

  __shared__ float redm[4], reds[4];
  if ((t & 63) == 0) redm[t >> 6] = m;
  __syncthreads();
  m = fmaxf(fmaxf(redm[0], redm[1]), fmaxf(redm[2], redm[3]));

  float e[8];
  float sum = 0.f;
  #pragma unroll
  for (int j = 0; j < 8; ++j) { e[j] = __expf(vals[j] - m); sum += e[j]; }
  #pragma unroll
  for (int off = 32; off >= 1; off >>= 1) sum += __shfl_xor(sum, off);
  if ((t & 63) == 0) reds[t >> 6] = sum;
  __syncthreads();
  sum = reds[0] + reds[1] + reds[2] + reds[3];
  const float inv = 1.f / sum;

  union { unsigned short us[8]; int4 v; } pk;
  #pragma unroll
  for (int j = 0; j < 8; ++j) pk.us[j] = f2bf(e[j] * inv);
  *reinterpret_cast<int4*>(P + (size_t)row * AD + t * 8) = pk.v;
}

extern "C" void kernel_launch(void* const* d_in, const int* in_sizes, int n_in,
                              void* d_out, int out_size, void* d_ws, size_t ws_size,
                              hipStream_t stream) {
  const float* z  = (const float*)d_in[0];
  const float* Wq = (const float*)d_in[1];
  const float* bq = (const float*)d_in[2];
  const float* Wk = (const float*)d_in[3];
  const float* bk = (const float*)d_in[4];
  const float* Wv = (const float*)d_in[5];
  const float* bv = (const float*)d_in[6];

  char* ws = (char*)d_ws;
  const size_t MB8 = (size_t)8 * 1024 * 1024;
  __hip_bfloat16* zb  = (__hip_bfloat16*)(ws);            // dead after QKV
  __hip_bfloat16* Wqb = (__hip_bfloat16*)(ws + MB8);      // dead after QKV
  __hip_bfloat16* Wkb = (__hip_bfloat16*)(ws + 2*MB8);    // dead after QKV
  __hip_bfloat16* vT  = (__hip_bfloat16*)(ws + 3*MB8);    // live until PV
  float*          S   = (float*)(ws);                     // over zb+Wqb (16MB)
  __hip_bfloat16* P   = (__hip_bfloat16*)(ws + 2*MB8);    // over Wkb
  __hip_bfloat16* qb  = (__hip_bfloat16*)d_out;           // d_out scratch [0:8)MB
  __hip_bfloat16* kb  = (__hip_bfloat16*)d_out + (size_t)AD * FD;  // [8:16)MB

  // 0) convert z, Wq, Wk to bf16 (Wv consumed f32 in-kernel)
  cvt_bf16<<<dim3(2048), dim3(256), 0, stream>>>(z, Wq, Wk, (__hip_bfloat16*)ws);

  // 1) fused QKV: (4,4) 4-wave 128^2, 768 blocks
  {
    GemmArgs a;
    a.A = zb;
    a.B[0] = Wqb; a.B[1] = Wkb; a.B[2] = Wv;
    a.bias[0] = bq; a.bias[1] = bk; a.bias[2] = bv;
    a.out[0] = qb; a.out[1] = kb; a.out[2] = vT;
    a.outmode[0] = 1; a.outmode[1] = 1; a.outmode[2] = 2;
    a.bf32mask = 0b100;
    a.scale = 1.0f;
    gemm_d<2, 2, 4, 4, -1, true, 3><<<dim3(AD/128, AD/128, 3), dim3(256), 0, stream>>>(a);
  }
  // 2) scores = (qb @ kb^T)/8 -> f32 S ; 128x64 8-wave, 512 blocks
  {
    GemmArgs a = {};
    a.A = qb;
    a.B[0] = kb;
    a.bias[0] = nullptr;
    a.out[0] = S;
    a.outmode[0] = 0;
    a.bf32mask = 0;
    a.scale = SM_SCALE;
    gemm_d<4, 2, 2, 2, 0, false, 4><<<dim3(AD/64, AD/128, 1), dim3(512), 0, stream>>>(a);
  }
  // 3) row softmax -> P bf16 (over Wkb)
  softmax_rows<<<dim3(AD), dim3(256), 0, stream>>>(S, P);
  // 4) h = P @ vT^T -> f32 d_out ; 128x64 8-wave, 512 blocks
  {
    GemmArgs a = {};
    a.A = P;
    a.B[0] = vT;
    a.bias[0] = nullptr;
    a.out[0] = d_out;
    a.outmode[0] = 0;
    a.bf32mask = 0;
    a.scale = 1.0f;
    gemm_d<4, 2, 2, 2, 0, false, 4><<<dim3(AD/64, AD/128, 1), dim3(512), 0, stream>>>(a);
  }
}